// Round 12
// baseline (708.156 us; speedup 1.0000x reference)
//
#include <hip/hip_runtime.h>

#define N_NODES 10000
#define E_EDGES 320000
#define F_IN    256
#define F_PROJ  200

typedef float vfloat4 __attribute__((ext_vector_type(4)));

#define N4_TOTAL 25000000L          // ev / edge_attr in float4s
#define S1_SPLIT 4000000L           // float4s copied by K1 (128 MB traffic)

#define K1_PROJ_BLOCKS 1250
#define K1_COPY_BLOCKS 768
#define K2_BLOCKS 6144              // role = bid & 3; 0 -> alpha/agg, 1..3 copy
#define K2_ALPHA_BLOCKS 1536
#define K2_COPY_BLOCKS (K2_BLOCKS - K2_ALPHA_BLOCKS)          // 4608
#define K2_ALPHA_WAVES (K2_ALPHA_BLOCKS * 4)
#define ALPHA_CHUNK ((E_EDGES + K2_ALPHA_WAVES - 1) / K2_ALPHA_WAVES)  // 53
#define AGG_N4 (N_NODES * F_IN / 4)                           // 640000
#define AGG_CHUNK ((AGG_N4 + K2_ALPHA_BLOCKS - 1) / K2_ALPHA_BLOCKS)  // 417

// workspace layout (5.33 MB)
#define WS_P      0L           // 4,000,000  (bf16 P)
#define WS_EXP    4000000L     // 1,280,000  (expalpha)
#define WS_FLAGS  5280000L     // 40,000
#define WS_SUM    5320000L     // 16

__device__ __forceinline__ unsigned short f32_to_bf16(float f) {
    unsigned int u = __float_as_uint(f);
    u += 0x7FFFu + ((u >> 16) & 1u);
    return (unsigned short)(u >> 16);
}
__device__ __forceinline__ float bf16_to_f32(unsigned short b) {
    return __uint_as_float(((unsigned int)b) << 16);
}

// WIDE nt copy: 64 B per thread per iteration (4 consecutive float4 loads,
// then 4 nt stores) -> 4 KB contiguous per wave burst. Longer same-direction
// runs per bank = less read<->write turnaround loss (the ~4.4 TB/s suspect).
// Requires (end-beg) % 4 == 0 and beg % 4 == 0: every quad is all-in or
// all-out of range, so no partial-quad tail handling is needed.
__device__ __forceinline__ void nt_copy_wide(
        const vfloat4* __restrict__ src, vfloat4* __restrict__ dst,
        long beg, long end, long cid, long nblk, int tid) {
    long i = beg + (cid * 256 + tid) * 4;
    const long stride = nblk * 256 * 4;
    for (; i < end; i += stride) {
        vfloat4 v0 = __builtin_nontemporal_load(src + i);
        vfloat4 v1 = __builtin_nontemporal_load(src + i + 1);
        vfloat4 v2 = __builtin_nontemporal_load(src + i + 2);
        vfloat4 v3 = __builtin_nontemporal_load(src + i + 3);
        __builtin_nontemporal_store(v0, dst + i);
        __builtin_nontemporal_store(v1, dst + i + 1);
        __builtin_nontemporal_store(v2, dst + i + 2);
        __builtin_nontemporal_store(v3, dst + i + 3);
    }
}

// ---- K1: proj + flag-scan (1250 blocks) ∥ wide nt-copy [0,S1) (768) ---------
__global__ __launch_bounds__(256) void k1_proj_flags_copy(
        const float* __restrict__ x, const float* __restrict__ W,
        unsigned short* __restrict__ P, const int* __restrict__ ei,
        int* __restrict__ flags,
        const vfloat4* __restrict__ csrc, vfloat4* __restrict__ cdst) {
    int bid = blockIdx.x, tid = threadIdx.x;
    if (bid >= K1_PROJ_BLOCKS) {
        nt_copy_wide(csrc, cdst, 0L, S1_SPLIT,
                     bid - K1_PROJ_BLOCKS, K1_COPY_BLOCKS, tid);
        return;
    }
    int gt = bid * 256 + tid;                  // 1250*256 == E exactly
    flags[ei[E_EDGES + gt]] = 1;               // racy same-value store: fine

    __shared__ float xs[8][F_IN];
    int n0 = bid * 8;
    for (int i = tid; i < 8 * F_IN / 4; i += 256)
        ((float4*)xs)[i] = ((const float4*)(x + (long)n0 * F_IN))[i];
    __syncthreads();
    int j = tid;
    if (j >= F_PROJ) return;
    float acc[8] = {0.f,0.f,0.f,0.f,0.f,0.f,0.f,0.f};
    for (int k = 0; k < F_IN; ++k) {
        float w = W[k * F_PROJ + j];
        #pragma unroll
        for (int r = 0; r < 8; ++r) acc[r] += xs[r][k] * w;
    }
    #pragma unroll
    for (int r = 0; r < 8; ++r) P[(long)(n0 + r) * F_PROJ + j] = f32_to_bf16(acc[r]);
}

// ---- K2: alpha (1536) ∥ agg (tail of alpha blocks) ∥ wide nt-copy (4608) ----
__global__ __launch_bounds__(256) void k2_alpha_agg_copy(
        const int* __restrict__ ei, const unsigned short* __restrict__ P,
        const float* __restrict__ Watt, const float* __restrict__ batt,
        float* __restrict__ expalpha, float* __restrict__ sumbuf,
        const int* __restrict__ flags, const float4* __restrict__ x4,
        float4* __restrict__ agg4,
        const vfloat4* __restrict__ csrc, vfloat4* __restrict__ cdst) {
    int bid = blockIdx.x, tid = threadIdx.x;
    int role = bid & 3;
    if (role != 0) {
        long cid = (long)(bid >> 2) * 3 + (role - 1);   // 0..4607
        nt_copy_wide(csrc, cdst, S1_SPLIT, N4_TOTAL, cid, K2_COPY_BLOCKS, tid);
        return;
    }
    __shared__ float bsum;
    if (tid == 0) bsum = 0.f;
    __syncthreads();
    int aid = bid >> 2, wid = aid * 4 + (tid >> 6), lane = tid & 63;
    float4 w4 = make_float4(0.f, 0.f, 0.f, 0.f);
    if (lane < 50) w4 = ((const float4*)Watt)[lane];
    float bias = batt[0];
    int e0 = wid * ALPHA_CHUNK, e1 = min(e0 + ALPHA_CHUNK, E_EDGES);
    float lsum = 0.f;
    for (int e = e0; e < e1; ++e) {
        int s = ei[e], d = ei[E_EDGES + e];
        float acc = 0.f;
        if (lane < 50) {
            uint2 us = *(const uint2*)(P + (long)s * F_PROJ + lane * 4);
            uint2 ud = *(const uint2*)(P + (long)d * F_PROJ + lane * 4);
            acc = fabsf(bf16_to_f32((unsigned short)(ud.x & 0xFFFF)) -
                        bf16_to_f32((unsigned short)(us.x & 0xFFFF))) * w4.x
                + fabsf(bf16_to_f32((unsigned short)(ud.x >> 16)) -
                        bf16_to_f32((unsigned short)(us.x >> 16))) * w4.y
                + fabsf(bf16_to_f32((unsigned short)(ud.y & 0xFFFF)) -
                        bf16_to_f32((unsigned short)(us.y & 0xFFFF))) * w4.z
                + fabsf(bf16_to_f32((unsigned short)(ud.y >> 16)) -
                        bf16_to_f32((unsigned short)(us.y >> 16))) * w4.w;
        }
        #pragma unroll
        for (int off = 32; off; off >>= 1) acc += __shfl_down(acc, off);
        if (lane == 0) {
            float ea = expf(fmaxf(acc + bias, 0.f));   // alpha in [0,~6]: safe
            expalpha[e] = ea;
            lsum += ea;
        }
    }
    if (lane == 0) atomicAdd(&bsum, lsum);
    __syncthreads();
    if (tid == 0) atomicAdd(sumbuf, bsum);
    // agg: flags ready since K1
    long a0 = (long)aid * AGG_CHUNK;
    long a1 = a0 + AGG_CHUNK; if (a1 > AGG_N4) a1 = AGG_N4;
    for (long i = a0 + tid; i < a1; i += 256) {
        float4 v = x4[i];
        if (!flags[i >> 6]) v = make_float4(0.f, 0.f, 0.f, 0.f);
        agg4[i] = v;
    }
}

// ---- K3: scatter a into ev (after full copy) --------------------------------
__global__ __launch_bounds__(256) void k3_scatter(
        const int* __restrict__ ei, const float* __restrict__ expalpha,
        const float* __restrict__ sumbuf, float* __restrict__ ev) {
    int e = blockIdx.x * 256 + threadIdx.x;
    if (e >= E_EDGES) return;
    float a = expalpha[e] / sumbuf[0];
    int s = ei[e], d = ei[E_EDGES + e];
    ev[(long)s * N_NODES + d] = a;
    ev[(long)d * N_NODES + s] = a;
}

// ================= host ======================================================
extern "C" void kernel_launch(void* const* d_in, const int* in_sizes, int n_in,
                              void* d_out, int out_size, void* d_ws, size_t ws_size,
                              hipStream_t stream) {
    (void)in_sizes; (void)n_in; (void)out_size; (void)ws_size;
    const float* x         = (const float*)d_in[0];
    const float* edge_attr = (const float*)d_in[1];
    const int*   ei        = (const int*)d_in[2];
    const float* W_proj    = (const float*)d_in[3];
    // d_in[4] = b_proj: cancels in p_i - p_j, unused
    const float* W_att     = (const float*)d_in[5];
    const float* b_att     = (const float*)d_in[6];

    float* agg = (float*)d_out;
    float* ev  = (float*)d_out + (long)N_NODES * F_IN;
    char* ws = (char*)d_ws;

    unsigned short* P = (unsigned short*)(ws + WS_P);
    float* expalpha   = (float*)(ws + WS_EXP);
    int*   flags      = (int*)(ws + WS_FLAGS);
    float* sumbuf     = (float*)(ws + WS_SUM);

    hipMemsetAsync(ws + WS_FLAGS, 0, 40016, stream);

    k1_proj_flags_copy<<<K1_PROJ_BLOCKS + K1_COPY_BLOCKS, 256, 0, stream>>>(
        x, W_proj, P, ei, flags, (const vfloat4*)edge_attr, (vfloat4*)ev);

    k2_alpha_agg_copy<<<K2_BLOCKS, 256, 0, stream>>>(
        ei, P, W_att, b_att, expalpha, sumbuf, flags,
        (const float4*)x, (float4*)agg,
        (const vfloat4*)edge_attr, (vfloat4*)ev);

    k3_scatter<<<(E_EDGES + 255) / 256, 256, 0, stream>>>(
        ei, expalpha, sumbuf, ev);
}

// Round 13
// 249.085 us; speedup vs baseline: 2.8430x; 2.8430x over previous
//
#include <hip/hip_runtime.h>

#define N_NODES 10000
#define E_EDGES 320000
#define F_IN    256
#define F_PROJ  200

typedef float vfloat4 __attribute__((ext_vector_type(4)));

#define N4_TOTAL 25000000L          // ev / edge_attr in float4s
#define S1_SPLIT 4000000L           // float4s copied by K1 (128 MB traffic)

#define K1_PROJ_BLOCKS 1250
#define K1_COPY_BLOCKS 768
#define K2_BLOCKS 6144              // role = bid & 3; 0 -> alpha/agg, 1..3 copy
#define K2_ALPHA_BLOCKS 1536
#define K2_COPY_BLOCKS (K2_BLOCKS - K2_ALPHA_BLOCKS)          // 4608
#define K2_ALPHA_WAVES (K2_ALPHA_BLOCKS * 4)
#define ALPHA_CHUNK ((E_EDGES + K2_ALPHA_WAVES - 1) / K2_ALPHA_WAVES)  // 53
#define AGG_N4 (N_NODES * F_IN / 4)                           // 640000
#define AGG_CHUNK ((AGG_N4 + K2_ALPHA_BLOCKS - 1) / K2_ALPHA_BLOCKS)  // 417

// workspace layout (5.33 MB)
#define WS_P      0L           // 4,000,000  (bf16 P)
#define WS_EXP    4000000L     // 1,280,000  (expalpha)
#define WS_FLAGS  5280000L     // 40,000
#define WS_SUM    5320000L     // 16

__device__ __forceinline__ unsigned short f32_to_bf16(float f) {
    unsigned int u = __float_as_uint(f);
    u += 0x7FFFu + ((u >> 16) & 1u);
    return (unsigned short)(u >> 16);
}
__device__ __forceinline__ float bf16_to_f32(unsigned short b) {
    return __uint_as_float(((unsigned int)b) << 16);
}

// Burst nt copy, CORRECT idiom (R12 lesson): the 4-deep unroll offsets are
// +256/+512/+768 float4s so every load/store INSTRUCTION stays lane-contiguous
// (64 lanes x 16 B = 1 KB full lines -> no partial-line RMW), while each block
// walks contiguous 16 KB tiles (long same-direction runs per DRAM bank).
__device__ __forceinline__ void nt_copy_burst(
        const vfloat4* __restrict__ src, vfloat4* __restrict__ dst,
        long beg, long end, long cid, long nblk, int tid) {
    const long n    = end - beg;
    const long nt4  = n & ~1023L;              // largest multiple of 1024 f4
    long base = beg + cid * 1024 + tid;
    const long stride = nblk * 1024;
    for (; base < beg + nt4; base += stride) {
        vfloat4 v0 = __builtin_nontemporal_load(src + base);
        vfloat4 v1 = __builtin_nontemporal_load(src + base + 256);
        vfloat4 v2 = __builtin_nontemporal_load(src + base + 512);
        vfloat4 v3 = __builtin_nontemporal_load(src + base + 768);
        __builtin_nontemporal_store(v0, dst + base);
        __builtin_nontemporal_store(v1, dst + base + 256);
        __builtin_nontemporal_store(v2, dst + base + 512);
        __builtin_nontemporal_store(v3, dst + base + 768);
    }
    // tail (< 1024 f4): one coalesced single-f4 pass
    long t = beg + nt4 + cid * 256 + tid;
    if (t < end) {
        vfloat4 v = __builtin_nontemporal_load(src + t);
        __builtin_nontemporal_store(v, dst + t);
    }
}

// ---- K1: proj + flag-scan (1250 blocks) ∥ burst nt-copy [0,S1) (768) --------
__global__ __launch_bounds__(256) void k1_proj_flags_copy(
        const float* __restrict__ x, const float* __restrict__ W,
        unsigned short* __restrict__ P, const int* __restrict__ ei,
        int* __restrict__ flags,
        const vfloat4* __restrict__ csrc, vfloat4* __restrict__ cdst) {
    int bid = blockIdx.x, tid = threadIdx.x;
    if (bid >= K1_PROJ_BLOCKS) {
        nt_copy_burst(csrc, cdst, 0L, S1_SPLIT,
                      bid - K1_PROJ_BLOCKS, K1_COPY_BLOCKS, tid);
        return;
    }
    int gt = bid * 256 + tid;                  // 1250*256 == E exactly
    flags[ei[E_EDGES + gt]] = 1;               // racy same-value store: fine

    __shared__ float xs[8][F_IN];
    int n0 = bid * 8;
    for (int i = tid; i < 8 * F_IN / 4; i += 256)
        ((float4*)xs)[i] = ((const float4*)(x + (long)n0 * F_IN))[i];
    __syncthreads();
    int j = tid;
    if (j >= F_PROJ) return;
    float acc[8] = {0.f,0.f,0.f,0.f,0.f,0.f,0.f,0.f};
    for (int k = 0; k < F_IN; ++k) {
        float w = W[k * F_PROJ + j];
        #pragma unroll
        for (int r = 0; r < 8; ++r) acc[r] += xs[r][k] * w;
    }
    #pragma unroll
    for (int r = 0; r < 8; ++r) P[(long)(n0 + r) * F_PROJ + j] = f32_to_bf16(acc[r]);
}

// ---- K2: alpha+agg (1536, role 0) ∥ burst nt-copy [S1,N4) (4608) ------------
__global__ __launch_bounds__(256) void k2_alpha_agg_copy(
        const int* __restrict__ ei, const unsigned short* __restrict__ P,
        const float* __restrict__ Watt, const float* __restrict__ batt,
        float* __restrict__ expalpha, float* __restrict__ sumbuf,
        const int* __restrict__ flags, const float4* __restrict__ x4,
        float4* __restrict__ agg4,
        const vfloat4* __restrict__ csrc, vfloat4* __restrict__ cdst) {
    int bid = blockIdx.x, tid = threadIdx.x;
    int role = bid & 3;
    if (role != 0) {
        long cid = (long)(bid >> 2) * 3 + (role - 1);   // 0..4607
        nt_copy_burst(csrc, cdst, S1_SPLIT, N4_TOTAL, cid, K2_COPY_BLOCKS, tid);
        return;
    }
    __shared__ float bsum;
    if (tid == 0) bsum = 0.f;
    __syncthreads();
    int aid = bid >> 2, wid = aid * 4 + (tid >> 6), lane = tid & 63;
    float4 w4 = make_float4(0.f, 0.f, 0.f, 0.f);
    if (lane < 50) w4 = ((const float4*)Watt)[lane];
    float bias = batt[0];
    int e0 = wid * ALPHA_CHUNK, e1 = min(e0 + ALPHA_CHUNK, E_EDGES);
    float lsum = 0.f;
    for (int e = e0; e < e1; ++e) {
        int s = ei[e], d = ei[E_EDGES + e];
        float acc = 0.f;
        if (lane < 50) {
            uint2 us = *(const uint2*)(P + (long)s * F_PROJ + lane * 4);
            uint2 ud = *(const uint2*)(P + (long)d * F_PROJ + lane * 4);
            acc = fabsf(bf16_to_f32((unsigned short)(ud.x & 0xFFFF)) -
                        bf16_to_f32((unsigned short)(us.x & 0xFFFF))) * w4.x
                + fabsf(bf16_to_f32((unsigned short)(ud.x >> 16)) -
                        bf16_to_f32((unsigned short)(us.x >> 16))) * w4.y
                + fabsf(bf16_to_f32((unsigned short)(ud.y & 0xFFFF)) -
                        bf16_to_f32((unsigned short)(us.y & 0xFFFF))) * w4.z
                + fabsf(bf16_to_f32((unsigned short)(ud.y >> 16)) -
                        bf16_to_f32((unsigned short)(us.y >> 16))) * w4.w;
        }
        #pragma unroll
        for (int off = 32; off; off >>= 1) acc += __shfl_down(acc, off);
        if (lane == 0) {
            float ea = expf(fmaxf(acc + bias, 0.f));   // alpha in [0,~6]: safe
            expalpha[e] = ea;
            lsum += ea;
        }
    }
    if (lane == 0) atomicAdd(&bsum, lsum);
    __syncthreads();
    if (tid == 0) atomicAdd(sumbuf, bsum);
    // agg: flags ready since K1
    long a0 = (long)aid * AGG_CHUNK;
    long a1 = a0 + AGG_CHUNK; if (a1 > AGG_N4) a1 = AGG_N4;
    for (long i = a0 + tid; i < a1; i += 256) {
        float4 v = x4[i];
        if (!flags[i >> 6]) v = make_float4(0.f, 0.f, 0.f, 0.f);
        agg4[i] = v;
    }
}

// ---- K3: scatter a into ev (after full copy) --------------------------------
__global__ __launch_bounds__(256) void k3_scatter(
        const int* __restrict__ ei, const float* __restrict__ expalpha,
        const float* __restrict__ sumbuf, float* __restrict__ ev) {
    int e = blockIdx.x * 256 + threadIdx.x;
    if (e >= E_EDGES) return;
    float a = expalpha[e] / sumbuf[0];
    int s = ei[e], d = ei[E_EDGES + e];
    ev[(long)s * N_NODES + d] = a;
    ev[(long)d * N_NODES + s] = a;
}

// ================= host ======================================================
extern "C" void kernel_launch(void* const* d_in, const int* in_sizes, int n_in,
                              void* d_out, int out_size, void* d_ws, size_t ws_size,
                              hipStream_t stream) {
    (void)in_sizes; (void)n_in; (void)out_size; (void)ws_size;
    const float* x         = (const float*)d_in[0];
    const float* edge_attr = (const float*)d_in[1];
    const int*   ei        = (const int*)d_in[2];
    const float* W_proj    = (const float*)d_in[3];
    // d_in[4] = b_proj: cancels in p_i - p_j, unused
    const float* W_att     = (const float*)d_in[5];
    const float* b_att     = (const float*)d_in[6];

    float* agg = (float*)d_out;
    float* ev  = (float*)d_out + (long)N_NODES * F_IN;
    char* ws = (char*)d_ws;

    unsigned short* P = (unsigned short*)(ws + WS_P);
    float* expalpha   = (float*)(ws + WS_EXP);
    int*   flags      = (int*)(ws + WS_FLAGS);
    float* sumbuf     = (float*)(ws + WS_SUM);

    hipMemsetAsync(ws + WS_FLAGS, 0, 40016, stream);

    k1_proj_flags_copy<<<K1_PROJ_BLOCKS + K1_COPY_BLOCKS, 256, 0, stream>>>(
        x, W_proj, P, ei, flags, (const vfloat4*)edge_attr, (vfloat4*)ev);

    k2_alpha_agg_copy<<<K2_BLOCKS, 256, 0, stream>>>(
        ei, P, W_att, b_att, expalpha, sumbuf, flags,
        (const float4*)x, (float4*)agg,
        (const vfloat4*)edge_attr, (vfloat4*)ev);

    k3_scatter<<<(E_EDGES + 255) / 256, 256, 0, stream>>>(
        ei, expalpha, sumbuf, ev);
}